// Round 2
// baseline (147.909 us; speedup 1.0000x reference)
//
#include <hip/hip_runtime.h>

// xDeepFM CIN, MI355X (gfx950) — R11: cin_h occupancy doubling.
// R10 post-mortem: cin_h 55us @ MfmaUtil 41%, Occupancy 17% — MFMA-busy time
// equals the 21us floor spread over 2.6x wall time. Cap was 2 waves/SIMD from
// BOTH grid (512 = 2 blocks/CU) and unified regs (84 VGPR + 64 AGPR acc > 128).
// R11: 2 batches/block, grid 1024, wave = (row-half g, batch b): acc 64->32,
// ip 32->16 regs => ~110 unified < 128; LDS 18.4 KB => 4 blocks/CU = 4
// waves/SIMD. Latency hiding moves from ILP window (8-MFMA) to TLP.
// cin_out unchanged from R10.

typedef _Float16 f16;
typedef _Float16 f16x4 __attribute__((ext_vector_type(4)));
typedef _Float16 f16x8 __attribute__((ext_vector_type(8)));
typedef float f32x4 __attribute__((ext_vector_type(4)));
typedef float f32x16 __attribute__((ext_vector_type(16)));

#define HSTR 72      // h LDS row stride (f16): 144B = 9*16B, b128-aligned
#define PBS  5120    // pW per-batch stride (f16): p0(1024)+p1(2048)+p2(2048)

__device__ __forceinline__ f32x16 zero16() {
    f32x16 v;
#pragma unroll
    for (int i = 0; i < 16; ++i) v[i] = 0.0f;
    return v;
}

// ---------------- prep: W (fp32 row-major) -> f16 fragment-ordered ----------
// Fragment (mc, kk) = 512 f16; element lane*8+i =
//   W[rbase + mc*32 + (lane&31)][kk*16 + (lane>>5)*8 + i]
// Regions (f16 offsets): H0@0 (W0 r0..63, KK=64) | O0@65536 (W0 r64..127) |
// H1@131072 (W1 r0..63, KK=128) | O1@262144 (W1 r64..127) | O2@393216 (W2 all).
__global__ void __launch_bounds__(256)
prep_frag(const float* __restrict__ W0, const float* __restrict__ W1,
          const float* __restrict__ W2, f16* __restrict__ dst)
{
    int g = (blockIdx.x * 256 + threadIdx.x) * 8;    // grid = 320
    const float* src; int base, KK, rbase;
    if (g < 65536)       { src = W0; base = 0;      KK = 64;  rbase = 0;  }
    else if (g < 131072) { src = W0; base = 65536;  KK = 64;  rbase = 64; }
    else if (g < 262144) { src = W1; base = 131072; KK = 128; rbase = 0;  }
    else if (g < 393216) { src = W1; base = 262144; KK = 128; rbase = 64; }
    else                 { src = W2; base = 393216; KK = 128; rbase = 0;  }
    int local = g - base;
    int frag  = local >> 9;
    int lane  = (local >> 3) & 63;
    int kk    = frag % KK;
    int mc    = frag / KK;
    int row   = rbase + mc * 32 + (lane & 31);
    int col   = kk * 16 + (lane >> 5) * 8;
    int IC    = KK * 16;
    const float* s = src + (size_t)row * IC + col;
    f16x8 o;
#pragma unroll
    for (int i = 0; i < 8; ++i) o[i] = (f16)s[i];
    *(f16x8*)(dst + g) = o;
}

// ---- p-chunk: p rows [jb, jb+32) of one batch -> global (M=32,N=32,K=64) ---
__device__ __forceinline__ void p_chunk(const f16* __restrict__ hrows,
                                        const f16x8 (&pB)[4],
                                        f16* __restrict__ pdst, int t, int q)
{
    f32x16 acc = zero16();
#pragma unroll
    for (int s = 0; s < 4; ++s) {
        f16x8 a = *(const f16x8*)(hrows + t * HSTR + s * 16 + q * 8);
        acc = __builtin_amdgcn_mfma_f32_32x32x16_f16(a, pB[s], acc, 0, 0, 0);
    }
#pragma unroll
    for (int r = 0; r < 16; ++r) {
        int row = (r & 3) + 8 * (r >> 2) + 4 * q;
        pdst[row * 32 + t] = (f16)acc[r];
    }
}

// ---- h-GEMM: rows [g*32,+32), ALL 64 cols, ONE batch -----------------------
// Per j: 2 W-frag loads + 2 h-scalar LDS reads feed 4 MFMAs (129 SIMD-cyc).
// Ping-pong depth-2 (j, j+1 resident; refill j+2 => ~258 cyc in-flight).
// Latency hiding primarily via TLP (4 waves/SIMD).
template <int HJ>
__device__ __forceinline__ void h_gemm2(const f16* __restrict__ Hf,
                                        const f16* __restrict__ h,
                                        int lane8, int t,
                                        const f16x8 (&ip)[2][2],   // [kq][nh]
                                        f32x16 (&acc)[2])          // [nh]
{
    acc[0] = zero16(); acc[1] = zero16();
    const f16* Wp = Hf + lane8;
    f16x8 wf[2][2];   // [phase][kq]
    f16   sc[2][2];   // [phase][nh]
#pragma unroll
    for (int ph = 0; ph < 2; ++ph) {
        wf[ph][0] = *(const f16x8*)(Wp + (ph * 2 + 0) * 512);
        wf[ph][1] = *(const f16x8*)(Wp + (ph * 2 + 1) * 512);
        sc[ph][0] = h[ph * HSTR + t];
        sc[ph][1] = h[ph * HSTR + 32 + t];
    }
    for (int jj = 0; jj < HJ; jj += 2) {
#pragma unroll
        for (int ph = 0; ph < 2; ++ph) {
            f16x8 w0 = wf[ph][0], w1 = wf[ph][1];
            f16 s0 = sc[ph][0], s1 = sc[ph][1];
            int jn = jj + ph + 2;
            if (jn > HJ - 1) jn = HJ - 1;              // clamped refill
            wf[ph][0] = *(const f16x8*)(Wp + (jn * 2 + 0) * 512);
            wf[ph][1] = *(const f16x8*)(Wp + (jn * 2 + 1) * 512);
            sc[ph][0] = h[jn * HSTR + t];
            sc[ph][1] = h[jn * HSTR + 32 + t];
            acc[0] = __builtin_amdgcn_mfma_f32_32x32x16_f16(w0, ip[0][0] * s0, acc[0], 0, 0, 0);
            acc[0] = __builtin_amdgcn_mfma_f32_32x32x16_f16(w1, ip[1][0] * s0, acc[0], 0, 0, 0);
            acc[1] = __builtin_amdgcn_mfma_f32_32x32x16_f16(w0, ip[0][1] * s1, acc[1], 0, 0, 0);
            acc[1] = __builtin_amdgcn_mfma_f32_32x32x16_f16(w1, ip[1][1] * s1, acc[1], 0, 0, 0);
        }
    }
}

__device__ __forceinline__ void load_bias(const float* __restrict__ bl,
                                          float (&bve)[16], int g, int q)
{
#pragma unroll
    for (int r = 0; r < 16; ++r)
        bve[r] = bl[g * 32 + (r & 3) + 8 * (r >> 2) + 4 * q];
}

// Write h_{l+1} rows [g*32,+32), all 64 cols, wave's batch.
__device__ __forceinline__ void epi2(const f32x16 (&acc)[2],
                                     f16* __restrict__ hd,
                                     const float (&bve)[16], int g, int t, int q)
{
#pragma unroll
    for (int r = 0; r < 16; ++r) {
        int row = g * 32 + (r & 3) + 8 * (r >> 2) + 4 * q;
        hd[row * HSTR + t]      = (f16)(acc[0][r] + bve[r]);
        hd[row * HSTR + 32 + t] = (f16)(acc[1][r] + bve[r]);
    }
}

// =================== Kernel 1: h-chain + p-vectors =========================
__global__ void __launch_bounds__(256, 4)
cin_h(const float* __restrict__ inp, const f16* __restrict__ Wf,
      f16* __restrict__ pW,
      const float* __restrict__ b0v, const float* __restrict__ b1v)
{
    __shared__ __attribute__((aligned(16))) f16 hL[2 * 64 * HSTR];  // 18432 B

    const int tid   = threadIdx.x;
    const int w     = tid >> 6;
    const int lane  = tid & 63;
    const int t     = lane & 31;
    const int q     = lane >> 5;
    const int lane8 = lane * 8;
    const int b     = w & 1;          // wave's local batch
    const int g     = w >> 1;         // row-half
    const int b0i   = blockIdx.x * 2;

    // Stage: 2 batches x 32 z-rows of inp (f32 coalesced) -> hL rows 0..31.
#pragma unroll
    for (int it = 0; it < 4; ++it) {
        int idx = it * 1024 + tid * 4;
        int bb = idx >> 11, rem = idx & 2047;
        int z = rem >> 6, k = rem & 63;
        f32x4 v = *(const f32x4*)(inp + (size_t)(b0i + bb) * 2048 + rem);
        f16x4 h4;
        h4[0] = (f16)v[0]; h4[1] = (f16)v[1]; h4[2] = (f16)v[2]; h4[3] = (f16)v[3];
        *(f16x4*)(hL + bb * 64 * HSTR + z * HSTR + k) = h4;
    }
    __syncthreads();                                   // B0: h0 (=inp) ready

    f16* hD = hL + b * 64 * HSTR;     // wave's batch h-buffer

    // ip[kq][nh][i] = inp[b][z=kq*16+q*8+i][nh*32+t]
    f16x8 ip[2][2];
#pragma unroll
    for (int kq = 0; kq < 2; ++kq)
#pragma unroll
        for (int nh = 0; nh < 2; ++nh) {
            f16x8 v;
#pragma unroll
            for (int i = 0; i < 8; ++i)
                v[i] = hD[(kq * 16 + q * 8 + i) * HSTR + nh * 32 + t];
            ip[kq][nh] = v;
        }
    // pB[s][i] = inp[b][z=t][k=s*16+q*8+i] — p-GEMM B-frags
    f16x8 pB[4];
#pragma unroll
    for (int s = 0; s < 4; ++s)
        pB[s] = *(const f16x8*)(hD + t * HSTR + s * 16 + q * 8);

    f16* pMy = pW + (size_t)(b0i + b) * PBS;
    const f16* H0 = Wf;
    const f16* H1 = Wf + 131072;
    f32x16 acc[2];
    float bve[16];

    // ---- Layer 0 (HJ=32) ----
    if (g == 0)
        p_chunk(hD, pB, pMy, t, q);                    // p0 rows 0..31
    h_gemm2<32>(H0 + g * 64 * 512, hD, lane8, t, ip, acc);
    load_bias(b0v, bve, g, q);
    __syncthreads();                                   // B1: all h0 reads done
    epi2(acc, hD, bve, g, t, q);                       // h1 rows g*32..+32
    __syncthreads();                                   // B2: h1 ready

    // ---- Layer 1 (HJ=64) ----
    p_chunk(hD + g * 32 * HSTR, pB, pMy + 1024 + g * 1024, t, q);
    h_gemm2<64>(H1 + g * 128 * 512, hD, lane8, t, ip, acc);
    load_bias(b1v, bve, g, q);
    __syncthreads();                                   // B3: all h1 reads done
    epi2(acc, hD, bve, g, t, q);                       // h1 -> h2 in place
    __syncthreads();                                   // B4: h2 ready

    p_chunk(hD + g * 32 * HSTR, pB, pMy + 3072 + g * 1024, t, q);
}

// =================== Kernel 2: out GEMMs (N = batch) =======================
// Block = (32-batch group) x (M=64 region).  Waves (mi, ki): m-tile x K-half.
// A coalesced frag loads; B-frags direct from global (lane t <-> batch row).
template <int S>
__device__ __forceinline__ void o_tile(const f16* __restrict__ Of,
                                       const f16* __restrict__ pBase,
                                       const float* __restrict__ biasp,
                                       float* __restrict__ out,
                                       float* __restrict__ rP,
                                       int bg, int colbase, int tid)
{
    const int w = tid >> 6, lane = tid & 63, t = lane & 31, q = lane >> 5;
    const int lane8 = lane * 8;
    const int mi = w & 1, ki = w >> 1;
    const f16* Ap = Of + (size_t)(mi * 2 * S + ki * S) * 512 + lane8;
    const f16* Bp = pBase + (size_t)(bg * 32 + t) * PBS + ki * S * 16 + q * 8;

    f32x16 acc = zero16();
    f16x8 af[4], bf[4];
#pragma unroll
    for (int i = 0; i < 4; ++i) {
        af[i] = *(const f16x8*)(Ap + i * 512);
        bf[i] = *(const f16x8*)(Bp + i * 16);
    }
#pragma unroll 4
    for (int s = 0; s < S; ++s) {
        int idx = s & 3;
        f16x8 a = af[idx], b = bf[idx];
        int sn = s + 4 < S ? s + 4 : S - 1;            // clamped refill
        af[idx] = *(const f16x8*)(Ap + sn * 512);
        bf[idx] = *(const f16x8*)(Bp + sn * 16);
        acc = __builtin_amdgcn_mfma_f32_32x32x16_f16(a, b, acc, 0, 0, 0);
    }
#pragma unroll
    for (int r = 0; r < 16; ++r) {
        int m = mi * 32 + (r & 3) + 8 * (r >> 2) + 4 * q;
        rP[(ki * 32 + t) * 64 + m] = acc[r];
    }
    __syncthreads();
#pragma unroll
    for (int it = 0; it < 2; ++it) {
        int idx4 = (it * 256 + tid) * 4;
        int n = idx4 >> 6, o = idx4 & 63;
        f32x4 v0 = *(const f32x4*)(rP + n * 64 + o);
        f32x4 v1 = *(const f32x4*)(rP + (32 + n) * 64 + o);
        f32x4 bb = *(const f32x4*)(biasp + o);
        f32x4 ov;
        ov[0] = v0[0] + v1[0] + 64.0f * bb[0];
        ov[1] = v0[1] + v1[1] + 64.0f * bb[1];
        ov[2] = v0[2] + v1[2] + 64.0f * bb[2];
        ov[3] = v0[3] + v1[3] + 64.0f * bb[3];
        *(f32x4*)(out + (size_t)(bg * 32 + n) * 256 + colbase + o) = ov;
    }
}

__global__ void __launch_bounds__(256, 2)
cin_out(const f16* __restrict__ Wf, const f16* __restrict__ pW,
        const float* __restrict__ b0v, const float* __restrict__ b1v,
        const float* __restrict__ b2v, float* __restrict__ out)
{
    __shared__ __attribute__((aligned(16))) float rP[2 * 32 * 64];  // 16 KB
    const int tid = threadIdx.x;
    const int r  = blockIdx.x & 3;      // region
    const int bg = blockIdx.x >> 2;     // 32-batch group (64 of them)
    if (r == 0)
        o_tile<32>(Wf + 65536,  pW,        b0v + 64, out, rP, bg, 0,   tid);
    else if (r == 1)
        o_tile<64>(Wf + 262144, pW + 1024, b1v + 64, out, rP, bg, 64,  tid);
    else if (r == 2)
        o_tile<64>(Wf + 393216, pW + 3072, b2v,      out, rP, bg, 128, tid);
    else
        o_tile<64>(Wf + 524288, pW + 3072, b2v + 64, out, rP, bg, 192, tid);
}

extern "C" void kernel_launch(void* const* d_in, const int* in_sizes, int n_in,
                              void* d_out, int out_size, void* d_ws, size_t ws_size,
                              hipStream_t stream)
{
    const float* inp = (const float*)d_in[0];
    const float* W0  = (const float*)d_in[1];
    const float* b0  = (const float*)d_in[2];
    const float* W1  = (const float*)d_in[3];
    const float* b1  = (const float*)d_in[4];
    const float* W2  = (const float*)d_in[5];
    const float* b2  = (const float*)d_in[6];
    float* out = (float*)d_out;

    f16* Wf = (f16*)d_ws;             // 655360 f16 = 1.25 MB fragment-ordered
    f16* pW = Wf + 655360;            // 2048 * 5120 f16 = 20 MB p-vectors

    prep_frag<<<320, 256, 0, stream>>>(W0, W1, W2, Wf);
    cin_h<<<1024, 256, 0, stream>>>(inp, Wf, pW, b0, b1);
    cin_out<<<256, 256, 0, stream>>>(Wf, pW, b0, b1, b2, out);
}

// Round 3
// 140.415 us; speedup vs baseline: 1.0534x; 1.0534x over previous
//
#include <hip/hip_runtime.h>

// xDeepFM CIN, MI355X (gfx950) — R12.
// R11 post-mortem: occupancy 17->31% as predicted but cin_h 55->62.5us,
// MfmaUtil 41->38%: halving the ILP window (8->4 MFMA per W-pair) cost more
// than 2x TLP gained; VALU:MFMA stayed 1:1 (VALUBusy 39 ~= MfmaUtil 38).
// => cin_h REVERTED to R10 structure (verified 55us).
// Real target: cin_out. Budget: total(139-148) - cin_h(55-62) - prep(~10)
// => cin_out ~40-55us, but MFMA floor 0.75us + HBM floor ~5us. It ran at
// grid=256 = 1 block/CU = 1 wave/SIMD: latency-bound at minimum occupancy.
// R12 cin_out: 512 thr / 8 waves = (mi, ki 4-way K-split), depth-8 prefetch,
// mi-pairs share B-rows in-CU, 4-way rP reduce in 32KB LDS. 2 waves/SIMD.

typedef _Float16 f16;
typedef _Float16 f16x4 __attribute__((ext_vector_type(4)));
typedef _Float16 f16x8 __attribute__((ext_vector_type(8)));
typedef float f32x4 __attribute__((ext_vector_type(4)));
typedef float f32x16 __attribute__((ext_vector_type(16)));

#define HSTR 72      // h LDS row stride (f16): 144B = 9*16B, b128-aligned
#define PBS  5120    // pW per-batch stride (f16): p0(1024)+p1(2048)+p2(2048)

__device__ __forceinline__ f32x16 zero16() {
    f32x16 v;
#pragma unroll
    for (int i = 0; i < 16; ++i) v[i] = 0.0f;
    return v;
}

// ---------------- prep: W (fp32 row-major) -> f16 fragment-ordered ----------
// Fragment (mc, kk) = 512 f16; element lane*8+i =
//   W[rbase + mc*32 + (lane&31)][kk*16 + (lane>>5)*8 + i]
// Regions (f16 offsets): H0@0 (W0 r0..63, KK=64) | O0@65536 (W0 r64..127) |
// H1@131072 (W1 r0..63, KK=128) | O1@262144 (W1 r64..127) | O2@393216 (W2 all).
__global__ void __launch_bounds__(256)
prep_frag(const float* __restrict__ W0, const float* __restrict__ W1,
          const float* __restrict__ W2, f16* __restrict__ dst)
{
    int g = (blockIdx.x * 256 + threadIdx.x) * 8;    // grid = 320
    const float* src; int base, KK, rbase;
    if (g < 65536)       { src = W0; base = 0;      KK = 64;  rbase = 0;  }
    else if (g < 131072) { src = W0; base = 65536;  KK = 64;  rbase = 64; }
    else if (g < 262144) { src = W1; base = 131072; KK = 128; rbase = 0;  }
    else if (g < 393216) { src = W1; base = 262144; KK = 128; rbase = 64; }
    else                 { src = W2; base = 393216; KK = 128; rbase = 0;  }
    int local = g - base;
    int frag  = local >> 9;
    int lane  = (local >> 3) & 63;
    int kk    = frag % KK;
    int mc    = frag / KK;
    int row   = rbase + mc * 32 + (lane & 31);
    int col   = kk * 16 + (lane >> 5) * 8;
    int IC    = KK * 16;
    const float* s = src + (size_t)row * IC + col;
    f16x8 o;
#pragma unroll
    for (int i = 0; i < 8; ++i) o[i] = (f16)s[i];
    *(f16x8*)(dst + g) = o;
}

// ---- p-chunk: p rows [jb, jb+32) of one batch -> global (M=32,N=32,K=64) ---
__device__ __forceinline__ void p_chunk(const f16* __restrict__ hrows,
                                        const f16x8 (&pB)[4],
                                        f16* __restrict__ pdst, int t, int q)
{
    f32x16 acc = zero16();
#pragma unroll
    for (int s = 0; s < 4; ++s) {
        f16x8 a = *(const f16x8*)(hrows + t * HSTR + s * 16 + q * 8);
        acc = __builtin_amdgcn_mfma_f32_32x32x16_f16(a, pB[s], acc, 0, 0, 0);
    }
#pragma unroll
    for (int r = 0; r < 16; ++r) {
        int row = (r & 3) + 8 * (r >> 2) + 4 * q;
        pdst[row * 32 + t] = (f16)acc[r];
    }
}

// ---- h-GEMM: rows [g*32,+32), ALL 64 cols, TWO batches ---------------------
// Per j: 2 W-frag loads feed 8 MFMAs (258 SIMD-cyc window > L2 latency).
// Ping-pong depth-2 (j, j+1 resident; refill j+2).
template <int HJ>
__device__ __forceinline__ void h_gemm4(const f16* __restrict__ Hf,
                                        const f16* __restrict__ h0,
                                        const f16* __restrict__ h1,
                                        int lane8, int t,
                                        const f16x8 (&ip)[2][2][2],   // [b][kq][nh]
                                        f32x16 (&acc)[2][2])          // [b][nh]
{
    acc[0][0] = zero16(); acc[0][1] = zero16();
    acc[1][0] = zero16(); acc[1][1] = zero16();
    const f16* Wp = Hf + lane8;
    f16x8 wf[2][2];   // [phase][kq]
    f16   sc[2][4];   // [phase][b*2+nh]
#pragma unroll
    for (int ph = 0; ph < 2; ++ph) {
        wf[ph][0] = *(const f16x8*)(Wp + (ph * 2 + 0) * 512);
        wf[ph][1] = *(const f16x8*)(Wp + (ph * 2 + 1) * 512);
        sc[ph][0] = h0[ph * HSTR + t];
        sc[ph][1] = h0[ph * HSTR + 32 + t];
        sc[ph][2] = h1[ph * HSTR + t];
        sc[ph][3] = h1[ph * HSTR + 32 + t];
    }
    for (int jj = 0; jj < HJ; jj += 2) {
#pragma unroll
        for (int ph = 0; ph < 2; ++ph) {
            f16x8 w0 = wf[ph][0], w1 = wf[ph][1];
            f16 s00 = sc[ph][0], s01 = sc[ph][1];
            f16 s10 = sc[ph][2], s11 = sc[ph][3];
            int jn = jj + ph + 2;
            if (jn > HJ - 1) jn = HJ - 1;              // clamped refill
            wf[ph][0] = *(const f16x8*)(Wp + (jn * 2 + 0) * 512);
            wf[ph][1] = *(const f16x8*)(Wp + (jn * 2 + 1) * 512);
            sc[ph][0] = h0[jn * HSTR + t];
            sc[ph][1] = h0[jn * HSTR + 32 + t];
            sc[ph][2] = h1[jn * HSTR + t];
            sc[ph][3] = h1[jn * HSTR + 32 + t];
            acc[0][0] = __builtin_amdgcn_mfma_f32_32x32x16_f16(w0, ip[0][0][0] * s00, acc[0][0], 0, 0, 0);
            acc[0][0] = __builtin_amdgcn_mfma_f32_32x32x16_f16(w1, ip[0][1][0] * s00, acc[0][0], 0, 0, 0);
            acc[0][1] = __builtin_amdgcn_mfma_f32_32x32x16_f16(w0, ip[0][0][1] * s01, acc[0][1], 0, 0, 0);
            acc[0][1] = __builtin_amdgcn_mfma_f32_32x32x16_f16(w1, ip[0][1][1] * s01, acc[0][1], 0, 0, 0);
            acc[1][0] = __builtin_amdgcn_mfma_f32_32x32x16_f16(w0, ip[1][0][0] * s10, acc[1][0], 0, 0, 0);
            acc[1][0] = __builtin_amdgcn_mfma_f32_32x32x16_f16(w1, ip[1][1][0] * s10, acc[1][0], 0, 0, 0);
            acc[1][1] = __builtin_amdgcn_mfma_f32_32x32x16_f16(w0, ip[1][0][1] * s11, acc[1][1], 0, 0, 0);
            acc[1][1] = __builtin_amdgcn_mfma_f32_32x32x16_f16(w1, ip[1][1][1] * s11, acc[1][1], 0, 0, 0);
        }
    }
}

__device__ __forceinline__ void load_bias(const float* __restrict__ bl,
                                          float (&bve)[16], int g, int q)
{
#pragma unroll
    for (int r = 0; r < 16; ++r)
        bve[r] = bl[g * 32 + (r & 3) + 8 * (r >> 2) + 4 * q];
}

// Write h_{l+1} rows [g*32,+32), all 64 cols, both batches.
__device__ __forceinline__ void epi4(const f32x16 (&acc)[2][2],
                                     f16* __restrict__ h0d, f16* __restrict__ h1d,
                                     const float (&bve)[16], int g, int t, int q)
{
#pragma unroll
    for (int r = 0; r < 16; ++r) {
        int row = g * 32 + (r & 3) + 8 * (r >> 2) + 4 * q;
        h0d[row * HSTR + t]      = (f16)(acc[0][0][r] + bve[r]);
        h0d[row * HSTR + 32 + t] = (f16)(acc[0][1][r] + bve[r]);
        h1d[row * HSTR + t]      = (f16)(acc[1][0][r] + bve[r]);
        h1d[row * HSTR + 32 + t] = (f16)(acc[1][1][r] + bve[r]);
    }
}

// =================== Kernel 1: h-chain + p-vectors (R10 verbatim) ==========
__global__ void __launch_bounds__(256, 2)
cin_h(const float* __restrict__ inp, const f16* __restrict__ Wf,
      f16* __restrict__ pW,
      const float* __restrict__ b0v, const float* __restrict__ b1v)
{
    __shared__ __attribute__((aligned(16))) f16 hL[4 * 64 * HSTR];  // 36864 B

    const int tid   = threadIdx.x;
    const int w     = tid >> 6;
    const int lane  = tid & 63;
    const int t     = lane & 31;
    const int q     = lane >> 5;
    const int lane8 = lane * 8;
    const int bp    = w & 1;          // batch-pair (local batches bp*2, bp*2+1)
    const int g     = w >> 1;         // row-half
    const int b0i   = blockIdx.x * 4;

    // Stage: 4 batches x 32 z-rows of inp (f32 coalesced) -> hL rows 0..31.
#pragma unroll
    for (int it = 0; it < 8; ++it) {
        int idx = it * 1024 + tid * 4;
        int b = idx >> 11, rem = idx & 2047;
        int z = rem >> 6, k = rem & 63;
        f32x4 v = *(const f32x4*)(inp + (size_t)(b0i + b) * 2048 + rem);
        f16x4 h4;
        h4[0] = (f16)v[0]; h4[1] = (f16)v[1]; h4[2] = (f16)v[2]; h4[3] = (f16)v[3];
        *(f16x4*)(hL + b * 64 * HSTR + z * HSTR + k) = h4;
    }
    __syncthreads();                                   // B0: h0 (=inp) ready

    // ip[b][kq][nh][i] = inp[bp*2+b][z=kq*16+q*8+i][nh*32+t]
    f16x8 ip[2][2][2];
#pragma unroll
    for (int b = 0; b < 2; ++b) {
        const f16* src = hL + (bp * 2 + b) * 64 * HSTR;
#pragma unroll
        for (int kq = 0; kq < 2; ++kq)
#pragma unroll
            for (int nh = 0; nh < 2; ++nh) {
                f16x8 v;
#pragma unroll
                for (int i = 0; i < 8; ++i)
                    v[i] = src[(kq * 16 + q * 8 + i) * HSTR + nh * 32 + t];
                ip[b][kq][nh] = v;
            }
    }
    // pB[s][i] = inp[w][z=t][k=s*16+q*8+i] — p-GEMM B-frags (wave w <-> batch w)
    f16x8 pB[4];
#pragma unroll
    for (int s = 0; s < 4; ++s)
        pB[s] = *(const f16x8*)(hL + w * 64 * HSTR + t * HSTR + s * 16 + q * 8);

    f16* pMy = pW + (size_t)(b0i + w) * PBS;
    const f16* H0 = Wf;
    const f16* H1 = Wf + 131072;
    f16* hA = hL + (bp * 2) * 64 * HSTR;
    f16* hB = hL + (bp * 2 + 1) * 64 * HSTR;
    f32x16 acc[2][2];
    float bve[16];

    // ---- Layer 0 (HJ=32) ----
    p_chunk(hL + w * 64 * HSTR, pB, pMy, t, q);        // p0: wave w, batch w
    h_gemm4<32>(H0 + g * 64 * 512, hA, hB, lane8, t, ip, acc);
    load_bias(b0v, bve, g, q);
    __syncthreads();                                   // B1: all h0 reads done
    epi4(acc, hA, hB, bve, g, t, q);                   // h1 (rows 0..63)
    __syncthreads();                                   // B2: h1 ready

    // ---- Layer 1 (HJ=64) ----
    p_chunk(hL + w * 64 * HSTR,             pB, pMy + 1024, t, q);
    p_chunk(hL + w * 64 * HSTR + 32 * HSTR, pB, pMy + 2048, t, q);
    h_gemm4<64>(H1 + g * 128 * 512, hA, hB, lane8, t, ip, acc);
    load_bias(b1v, bve, g, q);
    __syncthreads();                                   // B3: all h1 reads done
    epi4(acc, hA, hB, bve, g, t, q);                   // h1 -> h2 in place
    __syncthreads();                                   // B4: h2 ready

    p_chunk(hL + w * 64 * HSTR,             pB, pMy + 3072, t, q);
    p_chunk(hL + w * 64 * HSTR + 32 * HSTR, pB, pMy + 4096, t, q);
}

// =================== Kernel 2: out GEMMs (N = batch), R12 ==================
// Block = 512 thr (8 waves), one (32-batch group) x (M=64 region).
// Waves (mi = w&1, ki = w>>2..): mi = M-half, ki = K-quarter. mi-pairs read
// identical B rows (in-CU L1/L2 share). Depth-8 prefetch ring covers HBM
// latency on cold pW gathers. 4-way K partials reduced via 32KB LDS.
template <int KK>   // KK = total K-fragments (region0: 64, others: 128)
__device__ __forceinline__ void o_tile(const f16* __restrict__ Of,
                                       const f16* __restrict__ pBase,
                                       const float* __restrict__ biasp,
                                       float* __restrict__ out,
                                       float* __restrict__ rP,
                                       int bg, int colbase, int tid)
{
    const int w = tid >> 6, lane = tid & 63, t = lane & 31, q = lane >> 5;
    const int lane8 = lane * 8;
    const int mi = w & 1, ki = w >> 1;           // mi pairs adjacent -> B share
    const int SQ = KK / 4;                       // K-frags per wave (16 or 32)
    const f16* Ap = Of + (size_t)(mi * KK + ki * SQ) * 512 + lane8;
    const f16* Bp = pBase + (size_t)(bg * 32 + t) * PBS + (ki * SQ) * 16 + q * 8;

    f32x16 acc = zero16();
    f16x8 af[8], bf[8];
#pragma unroll
    for (int i = 0; i < 8; ++i) {
        af[i] = *(const f16x8*)(Ap + i * 512);
        bf[i] = *(const f16x8*)(Bp + i * 16);
    }
#pragma unroll 8
    for (int s = 0; s < SQ; ++s) {
        int idx = s & 7;
        f16x8 a = af[idx], b = bf[idx];
        int sn = s + 8 < SQ ? s + 8 : SQ - 1;    // clamped refill
        af[idx] = *(const f16x8*)(Ap + sn * 512);
        bf[idx] = *(const f16x8*)(Bp + sn * 16);
        acc = __builtin_amdgcn_mfma_f32_32x32x16_f16(a, b, acc, 0, 0, 0);
    }
#pragma unroll
    for (int r = 0; r < 16; ++r) {
        int m = mi * 32 + (r & 3) + 8 * (r >> 2) + 4 * q;
        rP[(ki * 32 + t) * 64 + m] = acc[r];
    }
    __syncthreads();
    // Combine: 512 thr x f32x4 = 2048 f32 (32 batches x 64 cols).
    {
        int n = tid >> 4;            // batch row 0..31
        int o = (tid & 15) * 4;      // col 0..60
        f32x4 v = *(const f32x4*)(rP + n * 64 + o);
#pragma unroll
        for (int k2 = 1; k2 < 4; ++k2) {
            f32x4 u = *(const f32x4*)(rP + (k2 * 32 + n) * 64 + o);
            v[0] += u[0]; v[1] += u[1]; v[2] += u[2]; v[3] += u[3];
        }
        f32x4 bb = *(const f32x4*)(biasp + o);
        v[0] += 64.0f * bb[0]; v[1] += 64.0f * bb[1];
        v[2] += 64.0f * bb[2]; v[3] += 64.0f * bb[3];
        *(f32x4*)(out + (size_t)(bg * 32 + n) * 256 + colbase + o) = v;
    }
}

__global__ void __launch_bounds__(512, 2)
cin_out(const f16* __restrict__ Wf, const f16* __restrict__ pW,
        const float* __restrict__ b0v, const float* __restrict__ b1v,
        const float* __restrict__ b2v, float* __restrict__ out)
{
    __shared__ __attribute__((aligned(16))) float rP[4 * 32 * 64];  // 32 KB
    const int tid = threadIdx.x;
    const int r  = blockIdx.x & 3;      // region
    const int bg = blockIdx.x >> 2;     // 32-batch group (64 of them)
    if (r == 0)
        o_tile<64> (Wf + 65536,  pW,        b0v + 64, out, rP, bg, 0,   tid);
    else if (r == 1)
        o_tile<128>(Wf + 262144, pW + 1024, b1v + 64, out, rP, bg, 64,  tid);
    else if (r == 2)
        o_tile<128>(Wf + 393216, pW + 3072, b2v,      out, rP, bg, 128, tid);
    else
        o_tile<128>(Wf + 524288, pW + 3072, b2v + 64, out, rP, bg, 192, tid);
}

extern "C" void kernel_launch(void* const* d_in, const int* in_sizes, int n_in,
                              void* d_out, int out_size, void* d_ws, size_t ws_size,
                              hipStream_t stream)
{
    const float* inp = (const float*)d_in[0];
    const float* W0  = (const float*)d_in[1];
    const float* b0  = (const float*)d_in[2];
    const float* W1  = (const float*)d_in[3];
    const float* b1  = (const float*)d_in[4];
    const float* W2  = (const float*)d_in[5];
    const float* b2  = (const float*)d_in[6];
    float* out = (float*)d_out;

    f16* Wf = (f16*)d_ws;             // 655360 f16 = 1.25 MB fragment-ordered
    f16* pW = Wf + 655360;            // 2048 * 5120 f16 = 20 MB p-vectors

    prep_frag<<<320, 256, 0, stream>>>(W0, W1, W2, Wf);
    cin_h<<<512, 256, 0, stream>>>(inp, Wf, pW, b0, b1);
    cin_out<<<256, 512, 0, stream>>>(Wf, pW, b0, b1, b2, out);
}

// Round 4
// 132.262 us; speedup vs baseline: 1.1183x; 1.0616x over previous
//
#include <hip/hip_runtime.h>

// xDeepFM CIN, MI355X (gfx950) — R13: fragment-ordered pW.
// R12 post-mortem: total-cin_h == ~84us CONSTANT across R10/R11/R12 despite
// cin_out restructure => either cin_out is ~50us in ALL forms (B-gather:
// lane t reads batch-row at 10KB stride, 32 scattered lines/load, 50% line
// util, L3-miss latency) or fixed overhead dominates. R13 discriminates by
// fixing the gather: pW stored in MFMA-fragment order per 32-batch group —
// frag f elem lane*8+i = P[b=lane&31][k=f*16+(lane>>5)*8+i]. cin_out B-load
// = one 1KB wave-coalesced load per frag (mi-pair shares addr -> L1 hit).
// Writer: f=j*2+(z>>4), off=((z>>3)&1)*256+(b&31)*8+(z&7); k=j*32+z matches
// prep_frag W-col order (verified algebra). Same MFMA ops, same rounding.
// cin_h R10-verbatim except p_chunk dst addressing.

typedef _Float16 f16;
typedef _Float16 f16x4 __attribute__((ext_vector_type(4)));
typedef _Float16 f16x8 __attribute__((ext_vector_type(8)));
typedef float f32x4 __attribute__((ext_vector_type(4)));
typedef float f32x16 __attribute__((ext_vector_type(16)));

#define HSTR 72      // h LDS row stride (f16): 144B = 9*16B, b128-aligned
#define GSTR 163840  // pW per-32-batch-group stride (f16): 320 frags * 512
#define P0G  0       // p0 frags [0,64)   within group
#define P1G  32768   // p1 frags [0,128)  within group
#define P2G  98304   // p2 frags [0,128)  within group

__device__ __forceinline__ f32x16 zero16() {
    f32x16 v;
#pragma unroll
    for (int i = 0; i < 16; ++i) v[i] = 0.0f;
    return v;
}

// ---------------- prep: W (fp32 row-major) -> f16 fragment-ordered ----------
// Fragment (mc, kk) = 512 f16; element lane*8+i =
//   W[rbase + mc*32 + (lane&31)][kk*16 + (lane>>5)*8 + i]
// Regions (f16 offsets): H0@0 (W0 r0..63, KK=64) | O0@65536 (W0 r64..127) |
// H1@131072 (W1 r0..63, KK=128) | O1@262144 (W1 r64..127) | O2@393216 (W2 all).
__global__ void __launch_bounds__(256)
prep_frag(const float* __restrict__ W0, const float* __restrict__ W1,
          const float* __restrict__ W2, f16* __restrict__ dst)
{
    int g = (blockIdx.x * 256 + threadIdx.x) * 8;    // grid = 320
    const float* src; int base, KK, rbase;
    if (g < 65536)       { src = W0; base = 0;      KK = 64;  rbase = 0;  }
    else if (g < 131072) { src = W0; base = 65536;  KK = 64;  rbase = 64; }
    else if (g < 262144) { src = W1; base = 131072; KK = 128; rbase = 0;  }
    else if (g < 393216) { src = W1; base = 262144; KK = 128; rbase = 64; }
    else                 { src = W2; base = 393216; KK = 128; rbase = 0;  }
    int local = g - base;
    int frag  = local >> 9;
    int lane  = (local >> 3) & 63;
    int kk    = frag % KK;
    int mc    = frag / KK;
    int row   = rbase + mc * 32 + (lane & 31);
    int col   = kk * 16 + (lane >> 5) * 8;
    int IC    = KK * 16;
    const float* s = src + (size_t)row * IC + col;
    f16x8 o;
#pragma unroll
    for (int i = 0; i < 8; ++i) o[i] = (f16)s[i];
    *(f16x8*)(dst + g) = o;
}

// ---- p-chunk: P rows [jb, jb+32) of one batch (M=32 j, N=32 z, K=64) ------
// Writes fragment-ordered: pdst = groupbase + regionoff + (b&31)*8.
__device__ __forceinline__ void p_chunk(const f16* __restrict__ hrows,
                                        const f16x8 (&pB)[4],
                                        f16* __restrict__ pdst, int jb,
                                        int t, int q)
{
    f32x16 acc = zero16();
#pragma unroll
    for (int s = 0; s < 4; ++s) {
        f16x8 a = *(const f16x8*)(hrows + t * HSTR + s * 16 + q * 8);
        acc = __builtin_amdgcn_mfma_f32_32x32x16_f16(a, pB[s], acc, 0, 0, 0);
    }
#pragma unroll
    for (int r = 0; r < 16; ++r) {
        int j = jb + (r & 3) + 8 * (r >> 2) + 4 * q;
        int f = j * 2 + (t >> 4);
        pdst[f * 512 + ((t >> 3) & 1) * 256 + (t & 7)] = (f16)acc[r];
    }
}

// ---- h-GEMM: rows [g*32,+32), ALL 64 cols, TWO batches ---------------------
// Per j: 2 W-frag loads feed 8 MFMAs (258 SIMD-cyc window > L2 latency).
// Ping-pong depth-2 (j, j+1 resident; refill j+2).
template <int HJ>
__device__ __forceinline__ void h_gemm4(const f16* __restrict__ Hf,
                                        const f16* __restrict__ h0,
                                        const f16* __restrict__ h1,
                                        int lane8, int t,
                                        const f16x8 (&ip)[2][2][2],   // [b][kq][nh]
                                        f32x16 (&acc)[2][2])          // [b][nh]
{
    acc[0][0] = zero16(); acc[0][1] = zero16();
    acc[1][0] = zero16(); acc[1][1] = zero16();
    const f16* Wp = Hf + lane8;
    f16x8 wf[2][2];   // [phase][kq]
    f16   sc[2][4];   // [phase][b*2+nh]
#pragma unroll
    for (int ph = 0; ph < 2; ++ph) {
        wf[ph][0] = *(const f16x8*)(Wp + (ph * 2 + 0) * 512);
        wf[ph][1] = *(const f16x8*)(Wp + (ph * 2 + 1) * 512);
        sc[ph][0] = h0[ph * HSTR + t];
        sc[ph][1] = h0[ph * HSTR + 32 + t];
        sc[ph][2] = h1[ph * HSTR + t];
        sc[ph][3] = h1[ph * HSTR + 32 + t];
    }
    for (int jj = 0; jj < HJ; jj += 2) {
#pragma unroll
        for (int ph = 0; ph < 2; ++ph) {
            f16x8 w0 = wf[ph][0], w1 = wf[ph][1];
            f16 s00 = sc[ph][0], s01 = sc[ph][1];
            f16 s10 = sc[ph][2], s11 = sc[ph][3];
            int jn = jj + ph + 2;
            if (jn > HJ - 1) jn = HJ - 1;              // clamped refill
            wf[ph][0] = *(const f16x8*)(Wp + (jn * 2 + 0) * 512);
            wf[ph][1] = *(const f16x8*)(Wp + (jn * 2 + 1) * 512);
            sc[ph][0] = h0[jn * HSTR + t];
            sc[ph][1] = h0[jn * HSTR + 32 + t];
            sc[ph][2] = h1[jn * HSTR + t];
            sc[ph][3] = h1[jn * HSTR + 32 + t];
            acc[0][0] = __builtin_amdgcn_mfma_f32_32x32x16_f16(w0, ip[0][0][0] * s00, acc[0][0], 0, 0, 0);
            acc[0][0] = __builtin_amdgcn_mfma_f32_32x32x16_f16(w1, ip[0][1][0] * s00, acc[0][0], 0, 0, 0);
            acc[0][1] = __builtin_amdgcn_mfma_f32_32x32x16_f16(w0, ip[0][0][1] * s01, acc[0][1], 0, 0, 0);
            acc[0][1] = __builtin_amdgcn_mfma_f32_32x32x16_f16(w1, ip[0][1][1] * s01, acc[0][1], 0, 0, 0);
            acc[1][0] = __builtin_amdgcn_mfma_f32_32x32x16_f16(w0, ip[1][0][0] * s10, acc[1][0], 0, 0, 0);
            acc[1][0] = __builtin_amdgcn_mfma_f32_32x32x16_f16(w1, ip[1][1][0] * s10, acc[1][0], 0, 0, 0);
            acc[1][1] = __builtin_amdgcn_mfma_f32_32x32x16_f16(w0, ip[1][0][1] * s11, acc[1][1], 0, 0, 0);
            acc[1][1] = __builtin_amdgcn_mfma_f32_32x32x16_f16(w1, ip[1][1][1] * s11, acc[1][1], 0, 0, 0);
        }
    }
}

__device__ __forceinline__ void load_bias(const float* __restrict__ bl,
                                          float (&bve)[16], int g, int q)
{
#pragma unroll
    for (int r = 0; r < 16; ++r)
        bve[r] = bl[g * 32 + (r & 3) + 8 * (r >> 2) + 4 * q];
}

// Write h_{l+1} rows [g*32,+32), all 64 cols, both batches.
__device__ __forceinline__ void epi4(const f32x16 (&acc)[2][2],
                                     f16* __restrict__ h0d, f16* __restrict__ h1d,
                                     const float (&bve)[16], int g, int t, int q)
{
#pragma unroll
    for (int r = 0; r < 16; ++r) {
        int row = g * 32 + (r & 3) + 8 * (r >> 2) + 4 * q;
        h0d[row * HSTR + t]      = (f16)(acc[0][0][r] + bve[r]);
        h0d[row * HSTR + 32 + t] = (f16)(acc[0][1][r] + bve[r]);
        h1d[row * HSTR + t]      = (f16)(acc[1][0][r] + bve[r]);
        h1d[row * HSTR + 32 + t] = (f16)(acc[1][1][r] + bve[r]);
    }
}

// =================== Kernel 1: h-chain + p-vectors =========================
__global__ void __launch_bounds__(256, 2)
cin_h(const float* __restrict__ inp, const f16* __restrict__ Wf,
      f16* __restrict__ pW,
      const float* __restrict__ b0v, const float* __restrict__ b1v)
{
    __shared__ __attribute__((aligned(16))) f16 hL[4 * 64 * HSTR];  // 36864 B

    const int tid   = threadIdx.x;
    const int w     = tid >> 6;
    const int lane  = tid & 63;
    const int t     = lane & 31;
    const int q     = lane >> 5;
    const int lane8 = lane * 8;
    const int bp    = w & 1;          // batch-pair (local batches bp*2, bp*2+1)
    const int g     = w >> 1;         // row-half
    const int b0i   = blockIdx.x * 4;

    // Stage: 4 batches x 32 z-rows of inp (f32 coalesced) -> hL rows 0..31.
#pragma unroll
    for (int it = 0; it < 8; ++it) {
        int idx = it * 1024 + tid * 4;
        int b = idx >> 11, rem = idx & 2047;
        int z = rem >> 6, k = rem & 63;
        f32x4 v = *(const f32x4*)(inp + (size_t)(b0i + b) * 2048 + rem);
        f16x4 h4;
        h4[0] = (f16)v[0]; h4[1] = (f16)v[1]; h4[2] = (f16)v[2]; h4[3] = (f16)v[3];
        *(f16x4*)(hL + b * 64 * HSTR + z * HSTR + k) = h4;
    }
    __syncthreads();                                   // B0: h0 (=inp) ready

    // ip[b][kq][nh][i] = inp[bp*2+b][z=kq*16+q*8+i][nh*32+t]
    f16x8 ip[2][2][2];
#pragma unroll
    for (int b = 0; b < 2; ++b) {
        const f16* src = hL + (bp * 2 + b) * 64 * HSTR;
#pragma unroll
        for (int kq = 0; kq < 2; ++kq)
#pragma unroll
            for (int nh = 0; nh < 2; ++nh) {
                f16x8 v;
#pragma unroll
                for (int i = 0; i < 8; ++i)
                    v[i] = src[(kq * 16 + q * 8 + i) * HSTR + nh * 32 + t];
                ip[b][kq][nh] = v;
            }
    }
    // pB[s][i] = inp[w][z=t][k=s*16+q*8+i] — p-GEMM B-frags (wave w <-> batch w)
    f16x8 pB[4];
#pragma unroll
    for (int s = 0; s < 4; ++s)
        pB[s] = *(const f16x8*)(hL + w * 64 * HSTR + t * HSTR + s * 16 + q * 8);

    const int bglob = b0i + w;        // wave w <-> batch w
    f16* pG = pW + (size_t)(bglob >> 5) * GSTR + (bglob & 31) * 8;
    const f16* H0 = Wf;
    const f16* H1 = Wf + 131072;
    f16* hA = hL + (bp * 2) * 64 * HSTR;
    f16* hB = hL + (bp * 2 + 1) * 64 * HSTR;
    f32x16 acc[2][2];
    float bve[16];

    // ---- Layer 0 (HJ=32) ----
    p_chunk(hL + w * 64 * HSTR, pB, pG + P0G, 0, t, q);     // p0 j 0..31
    h_gemm4<32>(H0 + g * 64 * 512, hA, hB, lane8, t, ip, acc);
    load_bias(b0v, bve, g, q);
    __syncthreads();                                   // B1: all h0 reads done
    epi4(acc, hA, hB, bve, g, t, q);                   // h1 (rows 0..63)
    __syncthreads();                                   // B2: h1 ready

    // ---- Layer 1 (HJ=64) ----
    p_chunk(hL + w * 64 * HSTR,             pB, pG + P1G, 0,  t, q);
    p_chunk(hL + w * 64 * HSTR + 32 * HSTR, pB, pG + P1G, 32, t, q);
    h_gemm4<64>(H1 + g * 128 * 512, hA, hB, lane8, t, ip, acc);
    load_bias(b1v, bve, g, q);
    __syncthreads();                                   // B3: all h1 reads done
    epi4(acc, hA, hB, bve, g, t, q);                   // h1 -> h2 in place
    __syncthreads();                                   // B4: h2 ready

    p_chunk(hL + w * 64 * HSTR,             pB, pG + P2G, 0,  t, q);
    p_chunk(hL + w * 64 * HSTR + 32 * HSTR, pB, pG + P2G, 32, t, q);
}

// =================== Kernel 2: out GEMMs (N = batch), R13 ==================
// Block = 512 thr (8 waves): mi = M-half, ki = K-quarter. B-frags now 1KB
// wave-coalesced (fragment-ordered pW); mi-pair reads identical addresses
// (L1 share). Depth-8 prefetch ring. 4-way K partials reduced via 32KB LDS.
template <int KK>   // KK = total K-fragments (region0: 64, others: 128)
__device__ __forceinline__ void o_tile(const f16* __restrict__ Of,
                                       const f16* __restrict__ pBase,
                                       const float* __restrict__ biasp,
                                       float* __restrict__ out,
                                       float* __restrict__ rP,
                                       int bg, int colbase, int tid)
{
    const int w = tid >> 6, lane = tid & 63, t = lane & 31, q = lane >> 5;
    const int lane8 = lane * 8;
    const int mi = w & 1, ki = w >> 1;           // mi pairs adjacent -> B share
    const int SQ = KK / 4;                       // K-frags per wave (16 or 32)
    const f16* Ap = Of + (size_t)(mi * KK + ki * SQ) * 512 + lane8;
    const f16* Bp = pBase + (size_t)(ki * SQ) * 512 + lane8;

    f32x16 acc = zero16();
    f16x8 af[8], bf[8];
#pragma unroll
    for (int i = 0; i < 8; ++i) {
        af[i] = *(const f16x8*)(Ap + i * 512);
        bf[i] = *(const f16x8*)(Bp + i * 512);
    }
#pragma unroll 8
    for (int s = 0; s < SQ; ++s) {
        int idx = s & 7;
        f16x8 a = af[idx], b = bf[idx];
        int sn = s + 8 < SQ ? s + 8 : SQ - 1;    // clamped refill
        af[idx] = *(const f16x8*)(Ap + sn * 512);
        bf[idx] = *(const f16x8*)(Bp + sn * 512);
        acc = __builtin_amdgcn_mfma_f32_32x32x16_f16(a, b, acc, 0, 0, 0);
    }
#pragma unroll
    for (int r = 0; r < 16; ++r) {
        int m = mi * 32 + (r & 3) + 8 * (r >> 2) + 4 * q;
        rP[(ki * 32 + t) * 64 + m] = acc[r];
    }
    __syncthreads();
    // Combine: 512 thr x f32x4 = 2048 f32 (32 batches x 64 cols).
    {
        int n = tid >> 4;            // batch row 0..31
        int o = (tid & 15) * 4;      // col 0..60
        f32x4 v = *(const f32x4*)(rP + n * 64 + o);
#pragma unroll
        for (int k2 = 1; k2 < 4; ++k2) {
            f32x4 u = *(const f32x4*)(rP + (k2 * 32 + n) * 64 + o);
            v[0] += u[0]; v[1] += u[1]; v[2] += u[2]; v[3] += u[3];
        }
        f32x4 bb = *(const f32x4*)(biasp + o);
        v[0] += 64.0f * bb[0]; v[1] += 64.0f * bb[1];
        v[2] += 64.0f * bb[2]; v[3] += 64.0f * bb[3];
        *(f32x4*)(out + (size_t)(bg * 32 + n) * 256 + colbase + o) = v;
    }
}

__global__ void __launch_bounds__(512, 2)
cin_out(const f16* __restrict__ Wf, const f16* __restrict__ pW,
        const float* __restrict__ b0v, const float* __restrict__ b1v,
        const float* __restrict__ b2v, float* __restrict__ out)
{
    __shared__ __attribute__((aligned(16))) float rP[4 * 32 * 64];  // 32 KB
    const int tid = threadIdx.x;
    const int r  = blockIdx.x & 3;      // region
    const int bg = blockIdx.x >> 2;     // 32-batch group (64 of them)
    const f16* pGrp = pW + (size_t)bg * GSTR;
    if (r == 0)
        o_tile<64> (Wf + 65536,  pGrp + P0G, b0v + 64, out, rP, bg, 0,   tid);
    else if (r == 1)
        o_tile<128>(Wf + 262144, pGrp + P1G, b1v + 64, out, rP, bg, 64,  tid);
    else if (r == 2)
        o_tile<128>(Wf + 393216, pGrp + P2G, b2v,      out, rP, bg, 128, tid);
    else
        o_tile<128>(Wf + 524288, pGrp + P2G, b2v + 64, out, rP, bg, 192, tid);
}

extern "C" void kernel_launch(void* const* d_in, const int* in_sizes, int n_in,
                              void* d_out, int out_size, void* d_ws, size_t ws_size,
                              hipStream_t stream)
{
    const float* inp = (const float*)d_in[0];
    const float* W0  = (const float*)d_in[1];
    const float* b0  = (const float*)d_in[2];
    const float* W1  = (const float*)d_in[3];
    const float* b1  = (const float*)d_in[4];
    const float* W2  = (const float*)d_in[5];
    const float* b2  = (const float*)d_in[6];
    float* out = (float*)d_out;

    f16* Wf = (f16*)d_ws;             // 655360 f16 = 1.25 MB fragment-ordered
    f16* pW = Wf + 655360;            // 64 groups * 163840 f16 = 20 MB

    prep_frag<<<320, 256, 0, stream>>>(W0, W1, W2, Wf);
    cin_h<<<512, 256, 0, stream>>>(inp, Wf, pW, b0, b1);
    cin_out<<<256, 512, 0, stream>>>(Wf, pW, b0, b1, b2, out);
}